// Round 3
// baseline (308.531 us; speedup 1.0000x reference)
//
#include <hip/hip_runtime.h>
#include <hip/hip_fp16.h>
#include <stdint.h>

#define BB      16
#define HH      32
#define HKVN    8
#define GG      4
#define DD      128
#define BLK     256
#define MAXBLKN 16
#define MAXCTXN 4096
#define NSLOTSN 65536
#define ATT_SCALE 0.08838834764831845f
#define QEPS    1e-8f

#define NSPLIT  16
#define CHUNK   256    // tokens per attention partial (= 1 physical kv block)

// output layout (all float32, concatenated in reference return order)
#define O_OFF   0
#define KC_OFF  65536
#define VC_OFF  (65536 + 67108864)
#define KSC_OFF (65536 + 2*67108864)
#define VSC_OFF (65536 + 2*67108864 + 524288)

// ws layout (floats): M[128][4][16], L[128][4][16], O[128][4][16][128]
#define WS_M    0
#define WS_L    8192
#define WS_O    16384

typedef float f32x4 __attribute__((ext_vector_type(4)));

// ---------------------------------------------------------------------------
// Region-fused kernel. One block per (h, physical kv block p): 2048 blocks.
//  Phase A: stream-convert the 128KB K region + 128KB V region + scale rows
//           (this IS the mandatory cache materialization, perfectly coalesced).
//  Phase B: for each (b, split) with block_table[b][split]==p (avg ~1), run
//           the attention partial for (b,h,split) re-reading the region from
//           L2/LLC (just streamed) -> attention adds ~zero HBM fetch traffic.
// Round-2 post-mortem: scheduling couldn't overlap copy and attention because
// both are HBM-pipe-bound; this version DEDUPLICATES the traffic instead
// (attn's ~270MB of K/V gather was a re-read of bytes the copy streams anyway).
// ---------------------------------------------------------------------------
__global__ __launch_bounds__(256) void fused_kernel(
    const float* __restrict__ q,
    const int* __restrict__ k_cache, const int* __restrict__ v_cache,
    const float* __restrict__ k_scale, const float* __restrict__ v_scale,
    const int* __restrict__ block_table, const int* __restrict__ context_lens,
    float* __restrict__ ws, float* __restrict__ out) {
  const int bid = blockIdx.x;          // 0..2047 = h*256 + p
  const int tid = threadIdx.x;
  const int h = bid >> 8;
  const int p = bid & 255;

  __shared__ __align__(16) float q_s[GG][DD];
  __shared__ __half p_s[GG][CHUNK];
  __shared__ float racc[8][32][17];    // +1 pad: conflict-free 8-way reduce
  __shared__ float red[GG][4];
  __shared__ int rlist[256];
  __shared__ int rcnt;

  if (tid == 0) rcnt = 0;
  __syncthreads();
  // find referencing (b, split) pairs: tid scans pair tid = b*16+s
  {
    const int b = tid >> 4, s = tid & 15;
    if (block_table[b * MAXBLKN + s] == p && s * CHUNK < context_lens[b])
      rlist[atomicAdd(&rcnt, 1)] = tid;
  }

  // ---- phase A: stream-convert K,V regions + scale rows for (h,p) ----
  const int base = p * BLK;            // physical slot base
  const int reg = h * NSLOTSN + base;  // row base (token rows)
  {
    const int4* srcK = (const int4*)k_cache + (long)reg * 32;
    const int4* srcV = (const int4*)v_cache + (long)reg * 32;
    f32x4* dstK = (f32x4*)(out + KC_OFF) + (long)reg * 32;
    f32x4* dstV = (f32x4*)(out + VC_OFF) + (long)reg * 32;
#pragma unroll 4
    for (int i = 0; i < 32; ++i) {
      int4 w = srcK[i * 256 + tid];
      f32x4 f;
      f.x = (float)w.x; f.y = (float)w.y; f.z = (float)w.z; f.w = (float)w.w;
      __builtin_nontemporal_store(f, dstK + i * 256 + tid);
    }
#pragma unroll 4
    for (int i = 0; i < 32; ++i) {
      int4 w = srcV[i * 256 + tid];
      f32x4 f;
      f.x = (float)w.x; f.y = (float)w.y; f.z = (float)w.z; f.w = (float)w.w;
      __builtin_nontemporal_store(f, dstV + i * 256 + tid);
    }
    if (tid < 64) {
      float4 w0 = ((const float4*)k_scale)[reg / 4 + tid];
      f32x4 w; w.x = w0.x; w.y = w0.y; w.z = w0.z; w.w = w0.w;
      __builtin_nontemporal_store(w, (f32x4*)(out + KSC_OFF) + reg / 4 + tid);
    } else if (tid < 128) {
      float4 w0 = ((const float4*)v_scale)[reg / 4 + (tid - 64)];
      f32x4 w; w.x = w0.x; w.y = w0.y; w.z = w0.z; w.w = w0.w;
      __builtin_nontemporal_store(w, (f32x4*)(out + VSC_OFF) + reg / 4 + (tid - 64));
    }
  }
  __syncthreads();
  const int nr = rcnt;
  if (nr == 0) return;

  const int lane = tid & 63;
  const int wid = tid >> 6;
  const int qlane = lane & 3;
  const int quad = lane >> 2;
  const int vlane = tid & 31;          // pass3: owns dims 4*vlane..4*vlane+3
  const int grp = tid >> 5;            // pass3: token subset

  for (int r = 0; r < nr; ++r) {
    const int pr = rlist[r];
    const int b = pr >> 4;
    const int s = pr & 15;             // split
    const int bh = b * HKVN + h;
    const int ctx = context_lens[b];
    const int n = min(CHUNK, ctx - s * CHUNK);

    for (int i = tid; i < GG * DD; i += 256)
      q_s[i >> 7][i & 127] = q[(b * HH + h * GG + (i >> 7)) * DD + (i & 127)];
    __syncthreads();

    // ---- pass 1: logits, quad-per-token (4 iters of 64 tokens) ----
    float lmax[GG] = {-1e30f, -1e30f, -1e30f, -1e30f};
#pragma unroll
    for (int it = 0; it < 4; ++it) {
      const int tok = it * 64 + wid * 16 + quad;
      const bool active = tok < n;
      const int slot = base + tok;
      float dot[GG] = {0.f, 0.f, 0.f, 0.f};
      if (active) {
        const int4* kr = (const int4*)(k_cache + (long)(h * NSLOTSN + slot) * DD);
#pragma unroll
        for (int kk = 0; kk < 8; ++kk) {
          int4 w = kr[qlane + 4 * kk];
          float k0 = (float)w.x, k1 = (float)w.y, k2 = (float)w.z, k3 = (float)w.w;
          const int c = (qlane + 4 * kk) * 4;
#pragma unroll
          for (int g = 0; g < GG; ++g) {
            float4 qv = *(const float4*)&q_s[g][c];
            dot[g] += qv.x * k0 + qv.y * k1 + qv.z * k2 + qv.w * k3;
          }
        }
      }
      // quad reduce (all 4 lanes end with full row dot)
#pragma unroll
      for (int g = 0; g < GG; ++g) {
        dot[g] += __shfl_xor(dot[g], 1);
        dot[g] += __shfl_xor(dot[g], 2);
      }
      if (active && qlane == 0) {
        float mult = k_scale[h * NSLOTSN + slot] * ATT_SCALE;
#pragma unroll
        for (int g = 0; g < GG; ++g) {
          float l = dot[g] * mult;
          p_s[g][tok] = __float2half(l);
          lmax[g] = fmaxf(lmax[g], l);
        }
      }
    }
#pragma unroll
    for (int g = 0; g < GG; ++g)
      for (int off = 32; off; off >>= 1)
        lmax[g] = fmaxf(lmax[g], __shfl_xor(lmax[g], off));
    if (lane == 0)
#pragma unroll
      for (int g = 0; g < GG; ++g) red[g][wid] = lmax[g];
    __syncthreads();
    float m[GG];
#pragma unroll
    for (int g = 0; g < GG; ++g)
      m[g] = fmaxf(fmaxf(red[g][0], red[g][1]), fmaxf(red[g][2], red[g][3]));

    // ---- pass 2: exp + sum (token-per-thread, single step) ----
    float lsum[GG] = {0.f, 0.f, 0.f, 0.f};
    if (tid < n) {
#pragma unroll
      for (int g = 0; g < GG; ++g) {
        float e = __expf(__half2float(p_s[g][tid]) - m[g]);
        p_s[g][tid] = __float2half(e);
        lsum[g] += e;
      }
    }
#pragma unroll
    for (int g = 0; g < GG; ++g)
      for (int off = 32; off; off >>= 1) lsum[g] += __shfl_xor(lsum[g], off);
    __syncthreads();  // red reuse
    if (lane == 0)
#pragma unroll
      for (int g = 0; g < GG; ++g) red[g][wid] = lsum[g];
    __syncthreads();
    float l[GG];
#pragma unroll
    for (int g = 0; g < GG; ++g)
      l[g] = red[g][0] + red[g][1] + red[g][2] + red[g][3];

    // ---- pass 3: PV. int4 V loads: 32 lanes/row, 8 parallel token groups ----
    float acc[GG][4] = {};
    const int vhb = h * NSLOTSN;
#pragma unroll 4
    for (int i = grp; i < n; i += 8) {
      int slot = base + i;
      float vs = v_scale[vhb + slot];
      int4 w = *(const int4*)(v_cache + (long)(vhb + slot) * DD + 4 * vlane);
      float v0 = (float)w.x * vs, v1 = (float)w.y * vs,
            v2 = (float)w.z * vs, v3 = (float)w.w * vs;
#pragma unroll
      for (int g = 0; g < GG; ++g) {
        float pw = __half2float(p_s[g][i]);
        acc[g][0] += pw * v0; acc[g][1] += pw * v1;
        acc[g][2] += pw * v2; acc[g][3] += pw * v3;
      }
    }
#pragma unroll
    for (int g = 0; g < GG; ++g)
#pragma unroll
      for (int j = 0; j < 4; ++j)
        racc[grp][vlane][g * 4 + j] = acc[g][j];
    __syncthreads();
    // 512 outputs (4 g x 128 d); 256 threads -> 2 each; 8-way sum from LDS
    for (int oidx = tid; oidx < 512; oidx += 256) {
      int gj = oidx & 15;
      int vl = oidx >> 4;
      float sacc = 0.f;
#pragma unroll
      for (int rr = 0; rr < 8; ++rr) sacc += racc[rr][vl][gj];
      int g = gj >> 2, j = gj & 3;
      ws[WS_O + (((bh * GG + g) * NSPLIT + s) * DD) + (vl * 4 + j)] = sacc;
    }
    if (tid == 0) {
#pragma unroll
      for (int g = 0; g < GG; ++g) {
        ws[WS_M + (bh * GG + g) * NSPLIT + s] = m[g];
        ws[WS_L + (bh * GG + g) * NSPLIT + s] = l[g];
      }
    }
    __syncthreads();  // safe reuse of q_s/p_s/racc next r
  }
}

// ---------------------------------------------------------------------------
// Kernel 2: blockIdx.x<128 -> combine partials (+current token); else
// quantize+store current k/v. 128 threads each.
// ---------------------------------------------------------------------------
__global__ __launch_bounds__(128) void finish_kernel(
    const float* __restrict__ q, const float* __restrict__ kin,
    const float* __restrict__ vin, const int* __restrict__ slot_mapping,
    const int* __restrict__ context_lens, float* __restrict__ out,
    const float* __restrict__ ws) {
  const int d = threadIdx.x;
  __shared__ float red[DD];
  __shared__ float lcur_s[GG];

  if (blockIdx.x < 128) {
    // ================= combine =================
    const int bh = blockIdx.x;
    const int h = bh & 7;
    const int b = bh >> 3;
    const int ctx = context_lens[b];
    const int nsp = (ctx + CHUNK - 1) / CHUNK;
    if (d < GG) {
      float dc = 0.f;
      const float* qp = q + (b * HH + h * GG + d) * DD;
      const float* kp = kin + (b * HKVN + h) * DD;
      for (int j = 0; j < DD; ++j) dc += qp[j] * kp[j];
      lcur_s[d] = dc * ATT_SCALE;
    }
    __syncthreads();
    float vcur = vin[(b * HKVN + h) * DD + d];
#pragma unroll
    for (int g = 0; g < GG; ++g) {
      float lc = lcur_s[g];
      float M = lc;
      for (int s = 0; s < nsp; ++s)
        M = fmaxf(M, ws[WS_M + (bh * GG + g) * NSPLIT + s]);
      float denom = __expf(lc - M);
      float o = denom * vcur;
      for (int s = 0; s < nsp; ++s) {
        float w = __expf(ws[WS_M + (bh * GG + g) * NSPLIT + s] - M);
        denom += ws[WS_L + (bh * GG + g) * NSPLIT + s] * w;
        o += ws[WS_O + ((bh * GG + g) * NSPLIT + s) * DD + d] * w;
      }
      out[O_OFF + (b * HH + h * GG + g) * DD + d] = o / denom;
    }
  } else {
    // ================= store-quant =================
    const int sid = blockIdx.x - 128;
    const int b = sid >> 3;
    const int h = sid & 7;
    const int slot = slot_mapping[b];
    for (int b2 = b + 1; b2 < BB; ++b2)
      if (slot_mapping[b2] == slot) return;  // numpy last-wins

    // K
    float xk = kin[(b * HKVN + h) * DD + d];
    red[d] = fabsf(xk);
    __syncthreads();
    for (int off = 64; off; off >>= 1) {
      if (d < off) red[d] = fmaxf(red[d], red[d + off]);
      __syncthreads();
    }
    float sk = fmaxf(red[0] / 127.0f, QEPS);
    __syncthreads();
    float qk = fminf(fmaxf(rintf(xk / sk), -127.0f), 127.0f);
    out[KC_OFF + (h * NSLOTSN + slot) * DD + d] = qk;
    if (d == 0) out[KSC_OFF + h * NSLOTSN + slot] = sk;

    // V
    float xv = vin[(b * HKVN + h) * DD + d];
    red[d] = fabsf(xv);
    __syncthreads();
    for (int off = 64; off; off >>= 1) {
      if (d < off) red[d] = fmaxf(red[d], red[d + off]);
      __syncthreads();
    }
    float sv = fmaxf(red[0] / 127.0f, QEPS);
    float qv = fminf(fmaxf(rintf(xv / sv), -127.0f), 127.0f);
    out[VC_OFF + (h * NSLOTSN + slot) * DD + d] = qv;
    if (d == 0) out[VSC_OFF + h * NSLOTSN + slot] = sv;
  }
}

extern "C" void kernel_launch(void* const* d_in, const int* in_sizes, int n_in,
                              void* d_out, int out_size, void* d_ws, size_t ws_size,
                              hipStream_t stream) {
  const float* q = (const float*)d_in[0];
  const float* k = (const float*)d_in[1];
  const float* v = (const float*)d_in[2];
  const int* k_cache = (const int*)d_in[3];
  const int* v_cache = (const int*)d_in[4];
  const float* k_scale = (const float*)d_in[5];
  const float* v_scale = (const float*)d_in[6];
  const int* slot_mapping = (const int*)d_in[7];
  const int* block_table = (const int*)d_in[8];
  const int* context_lens = (const int*)d_in[9];
  float* out = (float*)d_out;
  float* ws = (float*)d_ws;

  hipLaunchKernelGGL(fused_kernel, dim3(HKVN * 256), dim3(256), 0, stream,
                     q, k_cache, v_cache, k_scale, v_scale,
                     block_table, context_lens, ws, out);
  hipLaunchKernelGGL(finish_kernel, dim3(256), dim3(128), 0, stream,
                     q, k, v, slot_mapping, context_lens, out, ws);
}

// Round 4
// 290.233 us; speedup vs baseline: 1.0630x; 1.0630x over previous
//
#include <hip/hip_runtime.h>
#include <hip/hip_fp16.h>
#include <stdint.h>

#define BB      16
#define HH      32
#define HKVN    8
#define GG      4
#define DD      128
#define BLK     256
#define MAXBLKN 16
#define MAXCTXN 4096
#define NSLOTSN 65536
#define ATT_SCALE 0.08838834764831845f
#define QEPS    1e-8f

#define NSPLIT  16
#define CHUNK   256    // tokens per attention partial (= 1 physical kv block)

// output layout (all float32, concatenated in reference return order)
#define O_OFF   0
#define KC_OFF  65536
#define VC_OFF  (65536 + 67108864)
#define KSC_OFF (65536 + 2*67108864)
#define VSC_OFF (65536 + 2*67108864 + 524288)

// ws layout (floats): M[128][4][16], L[128][4][16], O[128][4][16][128]
#define WS_M    0
#define WS_L    8192
#define WS_O    16384

#define NREG    (HKVN * 256)           // 2048 region blocks (h,p)
#define NOVF    (256 * HKVN)           // 2048 overflow blocks (pair,h)

typedef float f32x4 __attribute__((ext_vector_type(4)));

// ---------------------------------------------------------------------------
// Round-4 structure. Grid = 4096:
//  bid < 2048  : region block (h = bid>>8, p = bid&255).
//     phase A: stream-convert 128KB K + 128KB V region + scale rows
//              (NORMAL stores now -- NT stores suspected of capping the
//              streaming-write path at ~4.7 TB/s vs 6.6 for plain fills).
//     phase B: at most ONE attention partial: the minimum-index (b,s) pair
//              with block_table[b][s]==p (region is L2-hot from phase A).
//  bid >= 2048 : overflow block (pair pi, head h). Runs the partial only if
//              pi references a region AND pi is not that region's min pair.
//              ~250 of 2048 are active; they launch after region blocks so
//              their region reads hit LLC. Uniform work => no straggler tail
//              (round-3 failure: blocks with 2-4 pairs serialized, avg
//              occupancy 25%, 160us tail at ~2 blocks/CU).
// ---------------------------------------------------------------------------
__global__ __launch_bounds__(256) void fused_kernel(
    const float* __restrict__ q,
    const int* __restrict__ k_cache, const int* __restrict__ v_cache,
    const float* __restrict__ k_scale, const float* __restrict__ v_scale,
    const int* __restrict__ block_table, const int* __restrict__ context_lens,
    float* __restrict__ ws, float* __restrict__ out) {
  const int bid = blockIdx.x;
  const int tid = threadIdx.x;

  __shared__ __align__(16) float q_s[GG][DD];
  __shared__ __half p_s[GG][CHUNK];
  __shared__ float racc[8][32][17];    // +1 pad: conflict-free 8-way reduce
  __shared__ float red[GG][4];
  __shared__ int minpair;
  __shared__ int ovf_p;

  int h, b, s;
  bool do_partial = false;

  if (bid < NREG) {
    // ================= region block =================
    h = bid >> 8;
    const int p = bid & 255;
    if (tid == 0) minpair = 0x7fffffff;
    __syncthreads();
    // scan: pair index t = b*16 + s (block_table layout is exactly [b][s])
    if (block_table[tid] == p && (tid & 15) * CHUNK < context_lens[tid >> 4])
      atomicMin(&minpair, tid);

    // ---- phase A: stream-convert K,V regions + scale rows for (h,p) ----
    const int reg = h * NSLOTSN + p * BLK;   // row base
    {
      const int4* srcK = (const int4*)k_cache + (size_t)reg * 32;
      const int4* srcV = (const int4*)v_cache + (size_t)reg * 32;
      f32x4* dstK = (f32x4*)(out + KC_OFF) + (size_t)reg * 32;
      f32x4* dstV = (f32x4*)(out + VC_OFF) + (size_t)reg * 32;
#pragma unroll 4
      for (int i = 0; i < 32; ++i) {
        int4 w = srcK[i * 256 + tid];
        f32x4 f;
        f.x = (float)w.x; f.y = (float)w.y; f.z = (float)w.z; f.w = (float)w.w;
        dstK[i * 256 + tid] = f;
      }
#pragma unroll 4
      for (int i = 0; i < 32; ++i) {
        int4 w = srcV[i * 256 + tid];
        f32x4 f;
        f.x = (float)w.x; f.y = (float)w.y; f.z = (float)w.z; f.w = (float)w.w;
        dstV[i * 256 + tid] = f;
      }
      if (tid < 64) {
        float4 w0 = ((const float4*)k_scale)[reg / 4 + tid];
        f32x4 w; w.x = w0.x; w.y = w0.y; w.z = w0.z; w.w = w0.w;
        ((f32x4*)(out + KSC_OFF))[reg / 4 + tid] = w;
      } else if (tid < 128) {
        float4 w0 = ((const float4*)v_scale)[reg / 4 + (tid - 64)];
        f32x4 w; w.x = w0.x; w.y = w0.y; w.z = w0.z; w.w = w0.w;
        ((f32x4*)(out + VSC_OFF))[reg / 4 + (tid - 64)] = w;
      }
    }
    __syncthreads();   // minpair visible (scan finished long ago)
    if (minpair == 0x7fffffff) return;
    b = minpair >> 4;
    s = minpair & 15;
    do_partial = true;
  } else {
    // ================= overflow block =================
    const int idx = bid - NREG;        // 0..2047
    const int pi = idx >> 3;           // pair index 0..255
    h = idx & 7;
    b = pi >> 4;
    s = pi & 15;
    if (s * CHUNK >= context_lens[b]) return;   // invalid pair
    if (tid == 0) {
      minpair = 0x7fffffff;
      ovf_p = block_table[pi];
    }
    __syncthreads();
    const int p = ovf_p;
    if (block_table[tid] == p && (tid & 15) * CHUNK < context_lens[tid >> 4])
      atomicMin(&minpair, tid);
    __syncthreads();
    if (minpair == pi) return;         // region block handles the min pair
    do_partial = true;
  }

  if (!do_partial) return;

  // ================= attention partial (b, h, s) =================
  const int bh = b * HKVN + h;
  const int ctx = context_lens[b];
  const int n = min(CHUNK, ctx - s * CHUNK);
  const int base = block_table[b * MAXBLKN + s] * BLK;
  const int lane = tid & 63;
  const int wid = tid >> 6;
  const int qlane = lane & 3;
  const int quad = lane >> 2;

  for (int i = tid; i < GG * DD; i += 256)
    q_s[i >> 7][i & 127] = q[(b * HH + h * GG + (i >> 7)) * DD + (i & 127)];
  __syncthreads();

  // ---- pass 1: logits, quad-per-token (4 iters of 64 tokens) ----
  float lmax[GG] = {-1e30f, -1e30f, -1e30f, -1e30f};
#pragma unroll
  for (int it = 0; it < 4; ++it) {
    const int tok = it * 64 + wid * 16 + quad;
    const bool active = tok < n;
    const int slot = base + tok;
    float dot[GG] = {0.f, 0.f, 0.f, 0.f};
    if (active) {
      const int4* kr = (const int4*)(k_cache + (size_t)(h * NSLOTSN + slot) * DD);
#pragma unroll
      for (int kk = 0; kk < 8; ++kk) {
        int4 w = kr[qlane + 4 * kk];
        float k0 = (float)w.x, k1 = (float)w.y, k2 = (float)w.z, k3 = (float)w.w;
        const int c = (qlane + 4 * kk) * 4;
#pragma unroll
        for (int g = 0; g < GG; ++g) {
          float4 qv = *(const float4*)&q_s[g][c];
          dot[g] += qv.x * k0 + qv.y * k1 + qv.z * k2 + qv.w * k3;
        }
      }
    }
    // quad reduce (all 4 lanes end with full row dot)
#pragma unroll
    for (int g = 0; g < GG; ++g) {
      dot[g] += __shfl_xor(dot[g], 1);
      dot[g] += __shfl_xor(dot[g], 2);
    }
    if (active && qlane == 0) {
      float mult = k_scale[h * NSLOTSN + slot] * ATT_SCALE;
#pragma unroll
      for (int g = 0; g < GG; ++g) {
        float l = dot[g] * mult;
        p_s[g][tok] = __float2half(l);
        lmax[g] = fmaxf(lmax[g], l);
      }
    }
  }
#pragma unroll
  for (int g = 0; g < GG; ++g)
    for (int off = 32; off; off >>= 1)
      lmax[g] = fmaxf(lmax[g], __shfl_xor(lmax[g], off));
  if (lane == 0)
#pragma unroll
    for (int g = 0; g < GG; ++g) red[g][wid] = lmax[g];
  __syncthreads();
  float m[GG];
#pragma unroll
  for (int g = 0; g < GG; ++g)
    m[g] = fmaxf(fmaxf(red[g][0], red[g][1]), fmaxf(red[g][2], red[g][3]));

  // ---- pass 2: exp + sum (token-per-thread, single step) ----
  float lsum[GG] = {0.f, 0.f, 0.f, 0.f};
  if (tid < n) {
#pragma unroll
    for (int g = 0; g < GG; ++g) {
      float e = __expf(__half2float(p_s[g][tid]) - m[g]);
      p_s[g][tid] = __float2half(e);
      lsum[g] += e;
    }
  }
#pragma unroll
  for (int g = 0; g < GG; ++g)
    for (int off = 32; off; off >>= 1) lsum[g] += __shfl_xor(lsum[g], off);
  __syncthreads();  // red reuse
  if (lane == 0)
#pragma unroll
    for (int g = 0; g < GG; ++g) red[g][wid] = lsum[g];
  __syncthreads();
  float l[GG];
#pragma unroll
  for (int g = 0; g < GG; ++g)
    l[g] = red[g][0] + red[g][1] + red[g][2] + red[g][3];

  // ---- pass 3: PV. int4 V loads: 32 lanes/row, 8 parallel token groups ----
  const int vlane = tid & 31;          // owns dims 4*vlane .. 4*vlane+3
  const int grp = tid >> 5;            // 0..7 token subset
  float acc[GG][4] = {};
  const int vhb = h * NSLOTSN;
#pragma unroll 4
  for (int i = grp; i < n; i += 8) {
    int slot = base + i;
    float vs = v_scale[vhb + slot];
    int4 w = *(const int4*)(v_cache + (size_t)(vhb + slot) * DD + 4 * vlane);
    float v0 = (float)w.x * vs, v1 = (float)w.y * vs,
          v2 = (float)w.z * vs, v3 = (float)w.w * vs;
#pragma unroll
    for (int g = 0; g < GG; ++g) {
      float pw = __half2float(p_s[g][i]);
      acc[g][0] += pw * v0; acc[g][1] += pw * v1;
      acc[g][2] += pw * v2; acc[g][3] += pw * v3;
    }
  }
#pragma unroll
  for (int g = 0; g < GG; ++g)
#pragma unroll
    for (int j = 0; j < 4; ++j)
      racc[grp][vlane][g * 4 + j] = acc[g][j];
  __syncthreads();
  // 512 outputs (4 g x 128 d); 256 threads -> 2 each; 8-way sum from LDS
  for (int oidx = tid; oidx < 512; oidx += 256) {
    int gj = oidx & 15;
    int vl = oidx >> 4;
    float sacc = 0.f;
#pragma unroll
    for (int rr = 0; rr < 8; ++rr) sacc += racc[rr][vl][gj];
    int g = gj >> 2, j = gj & 3;
    ws[WS_O + (((bh * GG + g) * NSPLIT + s) * DD) + (vl * 4 + j)] = sacc;
  }
  if (tid == 0) {
#pragma unroll
    for (int g = 0; g < GG; ++g) {
      ws[WS_M + (bh * GG + g) * NSPLIT + s] = m[g];
      ws[WS_L + (bh * GG + g) * NSPLIT + s] = l[g];
    }
  }
}

// ---------------------------------------------------------------------------
// Kernel 2: blockIdx.x<128 -> combine partials (+current token); else
// quantize+store current k/v. 128 threads each.
// ---------------------------------------------------------------------------
__global__ __launch_bounds__(128) void finish_kernel(
    const float* __restrict__ q, const float* __restrict__ kin,
    const float* __restrict__ vin, const int* __restrict__ slot_mapping,
    const int* __restrict__ context_lens, float* __restrict__ out,
    const float* __restrict__ ws) {
  const int d = threadIdx.x;
  __shared__ float red[DD];
  __shared__ float lcur_s[GG];

  if (blockIdx.x < 128) {
    // ================= combine =================
    const int bh = blockIdx.x;
    const int h = bh & 7;
    const int b = bh >> 3;
    const int ctx = context_lens[b];
    const int nsp = (ctx + CHUNK - 1) / CHUNK;
    if (d < GG) {
      float dc = 0.f;
      const float* qp = q + (b * HH + h * GG + d) * DD;
      const float* kp = kin + (b * HKVN + h) * DD;
      for (int j = 0; j < DD; ++j) dc += qp[j] * kp[j];
      lcur_s[d] = dc * ATT_SCALE;
    }
    __syncthreads();
    float vcur = vin[(b * HKVN + h) * DD + d];
#pragma unroll
    for (int g = 0; g < GG; ++g) {
      float lc = lcur_s[g];
      float M = lc;
      for (int s = 0; s < nsp; ++s)
        M = fmaxf(M, ws[WS_M + (bh * GG + g) * NSPLIT + s]);
      float denom = __expf(lc - M);
      float o = denom * vcur;
      for (int s = 0; s < nsp; ++s) {
        float w = __expf(ws[WS_M + (bh * GG + g) * NSPLIT + s] - M);
        denom += ws[WS_L + (bh * GG + g) * NSPLIT + s] * w;
        o += ws[WS_O + ((bh * GG + g) * NSPLIT + s) * DD + d] * w;
      }
      out[O_OFF + (b * HH + h * GG + g) * DD + d] = o / denom;
    }
  } else {
    // ================= store-quant =================
    const int sid = blockIdx.x - 128;
    const int b = sid >> 3;
    const int h = sid & 7;
    const int slot = slot_mapping[b];
    for (int b2 = b + 1; b2 < BB; ++b2)
      if (slot_mapping[b2] == slot) return;  // numpy last-wins

    // K
    float xk = kin[(b * HKVN + h) * DD + d];
    red[d] = fabsf(xk);
    __syncthreads();
    for (int off = 64; off; off >>= 1) {
      if (d < off) red[d] = fmaxf(red[d], red[d + off]);
      __syncthreads();
    }
    float sk = fmaxf(red[0] / 127.0f, QEPS);
    __syncthreads();
    float qk = fminf(fmaxf(rintf(xk / sk), -127.0f), 127.0f);
    out[KC_OFF + (h * NSLOTSN + slot) * DD + d] = qk;
    if (d == 0) out[KSC_OFF + h * NSLOTSN + slot] = sk;

    // V
    float xv = vin[(b * HKVN + h) * DD + d];
    red[d] = fabsf(xv);
    __syncthreads();
    for (int off = 64; off; off >>= 1) {
      if (d < off) red[d] = fmaxf(red[d], red[d + off]);
      __syncthreads();
    }
    float sv = fmaxf(red[0] / 127.0f, QEPS);
    float qv = fminf(fmaxf(rintf(xv / sv), -127.0f), 127.0f);
    out[VC_OFF + (h * NSLOTSN + slot) * DD + d] = qv;
    if (d == 0) out[VSC_OFF + h * NSLOTSN + slot] = sv;
  }
}

extern "C" void kernel_launch(void* const* d_in, const int* in_sizes, int n_in,
                              void* d_out, int out_size, void* d_ws, size_t ws_size,
                              hipStream_t stream) {
  const float* q = (const float*)d_in[0];
  const float* k = (const float*)d_in[1];
  const float* v = (const float*)d_in[2];
  const int* k_cache = (const int*)d_in[3];
  const int* v_cache = (const int*)d_in[4];
  const float* k_scale = (const float*)d_in[5];
  const float* v_scale = (const float*)d_in[6];
  const int* slot_mapping = (const int*)d_in[7];
  const int* block_table = (const int*)d_in[8];
  const int* context_lens = (const int*)d_in[9];
  float* out = (float*)d_out;
  float* ws = (float*)d_ws;

  hipLaunchKernelGGL(fused_kernel, dim3(NREG + NOVF), dim3(256), 0, stream,
                     q, k_cache, v_cache, k_scale, v_scale,
                     block_table, context_lens, ws, out);
  hipLaunchKernelGGL(finish_kernel, dim3(256), dim3(128), 0, stream,
                     q, k, v, slot_mapping, context_lens, out, ws);
}